// Round 6
// baseline (1963.776 us; speedup 1.0000x reference)
//
#include <hip/hip_runtime.h>

typedef unsigned int uint;
typedef unsigned short ushort;

// ---------- bf16 pack/unpack ----------
__device__ __forceinline__ float b2f(ushort u) {
    return __uint_as_float(((uint)u) << 16);
}
__device__ __forceinline__ uint f2bf(float f) {
    uint u = __float_as_uint(f);
    return (u + 0x7fffu + ((u >> 16) & 1u)) >> 16;
}
__device__ __forceinline__ uint pk2(float a, float b) {
    return f2bf(a) | (f2bf(b) << 16);
}

// ============================================================================
// FAST PIPELINE v4: edges counting-sorted by dst bucket of 256 nodes.
// k_gath: ONE LANE PER EDGE (1 coalesced eb load + 2 dwordx4 y loads/lane),
// padded LDS slab (row stride 17 floats) for bank spread.
// ============================================================================
#define PB 256             // partition stream slices

// ---- P1: per-(slice,bin) counts (u16 out) ----
__global__ __launch_bounds__(1024) void k_bcount(
    const int* __restrict__ row, const int* __restrict__ col,
    ushort* __restrict__ cnt, int E, int n, int NBINS, int SL)
{
    __shared__ uint h[4096];
    int t = threadIdx.x;
    for (int k = t; k < NBINS; k += 1024) h[k] = 0u;
    __syncthreads();
    int b = blockIdx.x;
    int s = b * SL;
    int end = s + SL; if (end > E) end = E;
    for (int e = s + t; e < end; e += 1024) {
        uint r = (uint)row[e], c = (uint)col[e];
        if (r < (uint)n && c < (uint)n) atomicAdd(&h[c >> 8], 1u);
    }
    __syncthreads();
    for (int k = t; k < NBINS; k += 1024)
        cnt[(size_t)b * NBINS + k] = (ushort)h[k];
}

// ---- P2a: column scan over 256 slices, 16 bins per block (LDS transpose) ----
__global__ __launch_bounds__(256) void k_scan1(
    ushort* __restrict__ cnt, uint* __restrict__ total, int NBINS)
{
    __shared__ uint tile[256 * 16];
    int t = threadIdx.x;
    int k0 = blockIdx.x * 16;
#pragma unroll
    for (int m = 0; m < 16; m++) {
        int lin = m * 256 + t;
        int b = lin >> 4, j = lin & 15;
        int k = k0 + j;
        tile[b * 16 + j] = (k < NBINS) ? (uint)cnt[(size_t)b * NBINS + k] : 0u;
    }
    __syncthreads();
    if (t < 16) {
        int k = k0 + t;
        uint run = 0u;
        for (int b = 0; b < 256; b++) {
            uint v = tile[b * 16 + t];
            tile[b * 16 + t] = run;     // exclusive prefix over slices
            run += v;
        }
        if (k < NBINS) total[k] = run;  // bin total
    }
    __syncthreads();
#pragma unroll
    for (int m = 0; m < 16; m++) {
        int lin = m * 256 + t;
        int b = lin >> 4, j = lin & 15;
        int k = k0 + j;
        if (k < NBINS) cnt[(size_t)b * NBINS + k] = (ushort)tile[b * 16 + j];
    }
}

// ---- P2b: scan bin totals -> base offsets (+sentinel base[NBINS]=E) ----
__global__ __launch_bounds__(256) void k_scan2(
    const uint* __restrict__ total, uint* __restrict__ base, int NBINS, int E)
{
    __shared__ uint ls[256];
    __shared__ uint carry;
    int t = threadIdx.x;
    if (t == 0) carry = 0u;
    __syncthreads();
    for (int off = 0; off < NBINS; off += 256) {
        int k = off + t;
        uint v = (k < NBINS) ? total[k] : 0u;
        ls[t] = v;
        __syncthreads();
        uint incl = v;
        for (int d = 1; d < 256; d <<= 1) {
            uint xv = (t >= d) ? ls[t - d] : 0u;
            __syncthreads();
            incl += xv;
            ls[t] = incl;
            __syncthreads();
        }
        if (k < NBINS) base[k] = carry + incl - v;
        __syncthreads();
        if (t == 255) carry += incl;
        __syncthreads();
    }
    if (t == 0) base[NBINS] = (uint)E;
}

// ---- P3: partition edges into bucket-sorted packed array ----
__global__ __launch_bounds__(1024) void k_part(
    const int* __restrict__ row, const int* __restrict__ col,
    const ushort* __restrict__ pos, const uint* __restrict__ base,
    uint* __restrict__ eb, int E, int n, int NBINS, int SL)
{
    __shared__ uint cur[4096];
    int t = threadIdx.x;
    int b = blockIdx.x;
    for (int k = t; k < NBINS; k += 1024)
        cur[k] = base[k] + (uint)pos[(size_t)b * NBINS + k];
    __syncthreads();
    int s = b * SL;
    int end = s + SL; if (end > E) end = E;
    for (int e = s + t; e < end; e += 1024) {
        uint r = (uint)row[e], c = (uint)col[e];
        if (r < (uint)n && c < (uint)n) {
            uint p = atomicAdd(&cur[c >> 8], 1u);
            eb[p] = (r << 8) | (c & 255u);
        }
    }
}

// ---- P4: per-bucket degree -> dis = rsqrt(deg+1) ----
__global__ __launch_bounds__(256) void k_bdeg(
    const uint* __restrict__ eb, const uint* __restrict__ base,
    float* __restrict__ dis, int n)
{
    __shared__ uint dg[256];
    int t = threadIdx.x;
    int k = blockIdx.x;
    dg[t] = 0u;
    __syncthreads();
    uint s = base[k], e_end = base[k + 1];
    for (uint i = s + t; i < e_end; i += 256)
        atomicAdd(&dg[eb[i] & 255u], 1u);
    __syncthreads();
    int i = (k << 8) + t;
    if (i < n) dis[i] = rsqrtf((float)dg[t] + 1.0f);
}

// ---- P5: xw = x@Wc, y = dis*xw (bf16 compact) ----
__global__ __launch_bounds__(256) void k_pre2(
    const float* __restrict__ xm, const float* __restrict__ dis,
    const float* __restrict__ Wc, uint* __restrict__ yws, int n)
{
    __shared__ float sW[256];
    int t = threadIdx.x;
    sW[t] = Wc[t];
    __syncthreads();
    int i = blockIdx.x * 256 + t;
    if (i >= n) return;

    const float4* xp = (const float4*)(xm + (size_t)i * 16);
    float xv[16];
    {
        float4 q0 = xp[0], q1 = xp[1], q2 = xp[2], q3 = xp[3];
        xv[0] = q0.x; xv[1] = q0.y; xv[2]  = q0.z; xv[3]  = q0.w;
        xv[4] = q1.x; xv[5] = q1.y; xv[6]  = q1.z; xv[7]  = q1.w;
        xv[8] = q2.x; xv[9] = q2.y; xv[10] = q2.z; xv[11] = q2.w;
        xv[12] = q3.x; xv[13] = q3.y; xv[14] = q3.z; xv[15] = q3.w;
    }
    float acc[16];
#pragma unroll
    for (int j = 0; j < 16; j++) acc[j] = 0.f;
#pragma unroll
    for (int k = 0; k < 16; k++) {
        float a = xv[k];
#pragma unroll
        for (int j = 0; j < 16; j++) acc[j] = fmaf(a, sW[k * 16 + j], acc[j]);
    }
    float d = dis[i];
    float v[16];
#pragma unroll
    for (int j = 0; j < 16; j++) v[j] = d * acc[j];

    uint4 p0, p1;
    p0.x = pk2(v[0], v[1]);   p0.y = pk2(v[2], v[3]);
    p0.z = pk2(v[4], v[5]);   p0.w = pk2(v[6], v[7]);
    p1.x = pk2(v[8], v[9]);   p1.y = pk2(v[10], v[11]);
    p1.z = pk2(v[12], v[13]); p1.w = pk2(v[14], v[15]);
    uint4* yw = (uint4*)(yws + (size_t)i * 8);
    yw[0] = p0; yw[1] = p1;
}

// ---- P6: gather, ONE LANE PER EDGE, padded slab; agg = slab + self-y ----
#define SST 17                         // slab row stride (floats), odd => bank spread
__device__ __forceinline__ void acc_edge(float* slab, uint w, uint4 a, uint4 b) {
    float* rp = slab + (w & 255u) * SST;
    atomicAdd(rp + 0,  __uint_as_float(a.x << 16));
    atomicAdd(rp + 1,  __uint_as_float(a.x & 0xffff0000u));
    atomicAdd(rp + 2,  __uint_as_float(a.y << 16));
    atomicAdd(rp + 3,  __uint_as_float(a.y & 0xffff0000u));
    atomicAdd(rp + 4,  __uint_as_float(a.z << 16));
    atomicAdd(rp + 5,  __uint_as_float(a.z & 0xffff0000u));
    atomicAdd(rp + 6,  __uint_as_float(a.w << 16));
    atomicAdd(rp + 7,  __uint_as_float(a.w & 0xffff0000u));
    atomicAdd(rp + 8,  __uint_as_float(b.x << 16));
    atomicAdd(rp + 9,  __uint_as_float(b.x & 0xffff0000u));
    atomicAdd(rp + 10, __uint_as_float(b.y << 16));
    atomicAdd(rp + 11, __uint_as_float(b.y & 0xffff0000u));
    atomicAdd(rp + 12, __uint_as_float(b.z << 16));
    atomicAdd(rp + 13, __uint_as_float(b.z & 0xffff0000u));
    atomicAdd(rp + 14, __uint_as_float(b.w << 16));
    atomicAdd(rp + 15, __uint_as_float(b.w & 0xffff0000u));
}

__global__ __launch_bounds__(256, 6) void k_gath(
    const uint* __restrict__ eb, const uint* __restrict__ base,
    const uint* __restrict__ yws, float* __restrict__ agg, int n)
{
    __shared__ float slab[256 * SST];   // 17.4 KB
    int t = threadIdx.x;
    for (int u = t; u < 256 * SST; u += 256) slab[u] = 0.f;
    __syncthreads();

    int k = blockIdx.x;
    uint estart = base[k];
    uint eend   = base[k + 1];

    uint ei = estart + (uint)t;
    // unroll x4: 4 independent edges per lane, 8 dwordx4 gathers in flight
    for (; ei + 768u < eend; ei += 1024u) {
        uint w0 = eb[ei], w1 = eb[ei + 256u], w2 = eb[ei + 512u], w3 = eb[ei + 768u];
        const uint4* y0 = (const uint4*)(yws + (size_t)(w0 >> 8) * 8);
        const uint4* y1 = (const uint4*)(yws + (size_t)(w1 >> 8) * 8);
        const uint4* y2 = (const uint4*)(yws + (size_t)(w2 >> 8) * 8);
        const uint4* y3 = (const uint4*)(yws + (size_t)(w3 >> 8) * 8);
        uint4 a0 = y0[0], b0 = y0[1];
        uint4 a1 = y1[0], b1 = y1[1];
        uint4 a2 = y2[0], b2 = y2[1];
        uint4 a3 = y3[0], b3 = y3[1];
        acc_edge(slab, w0, a0, b0);
        acc_edge(slab, w1, a1, b1);
        acc_edge(slab, w2, a2, b2);
        acc_edge(slab, w3, a3, b3);
    }
    for (; ei < eend; ei += 256u) {
        uint w = eb[ei];
        const uint4* yp = (const uint4*)(yws + (size_t)(w >> 8) * 8);
        uint4 a = yp[0], b = yp[1];
        acc_edge(slab, w, a, b);
    }
    __syncthreads();

    // flush: agg[i] = slab row + own y (self-loop term); pure store
    int nb = k << 8;
    for (int u = t; u < 1024; u += 256) {       // 1024 float4 stores
        int i = nb + (u >> 2);
        if (i >= n) break;
        int q = u & 3;
        const float* sp = slab + (size_t)(u >> 2) * SST + q * 4;
        uint2 p = ((const uint2*)(yws + (size_t)i * 8))[q];
        float4 sv = make_float4(sp[0], sp[1], sp[2], sp[3]);
        sv.x += __uint_as_float(p.x << 16);
        sv.y += __uint_as_float(p.x & 0xffff0000u);
        sv.z += __uint_as_float(p.y << 16);
        sv.w += __uint_as_float(p.y & 0xffff0000u);
        ((float4*)(agg + (size_t)i * 16))[q] = sv;
    }
}

// ---- P7: epilogue ----
__global__ __launch_bounds__(256) void k_post2(
    const float* __restrict__ agg_in, const float* __restrict__ dis,
    const float* __restrict__ Zt, const int* __restrict__ first,
    const float* __restrict__ bconv,
    const float* __restrict__ Wir, const float* __restrict__ bir,
    const float* __restrict__ Whr, const float* __restrict__ bhr,
    const float* __restrict__ Wiz, const float* __restrict__ biz,
    const float* __restrict__ Whz, const float* __restrict__ bhz,
    const float* __restrict__ Win, const float* __restrict__ bin_,
    const float* __restrict__ Whn, const float* __restrict__ bhn,
    const float* __restrict__ Wfc1, const float* __restrict__ bfc1,
    const float* __restrict__ Wfc2, const float* __restrict__ bfc2,
    float* outf, float* zbar, int n)
{
    __shared__ float s[1808];
    int t = threadIdx.x;
    s[t]        = Wir[t];
    s[256 + t]  = Whr[t];
    s[512 + t]  = Wiz[t];
    s[768 + t]  = Whz[t];
    s[1024 + t] = Win[t];
    s[1280 + t] = Whn[t];
    if (t < 16) {
        s[1536 + t] = bir[t];  s[1552 + t] = bhr[t];
        s[1568 + t] = biz[t];  s[1584 + t] = bhz[t];
        s[1600 + t] = bin_[t]; s[1616 + t] = bhn[t];
        s[1632 + t] = bconv[t];
        s[1784 + t] = Wfc2[t];
    }
    if (t < 128) s[1648 + t] = Wfc1[t];
    if (t < 8)   s[1776 + t] = bfc1[t];
    if (t < 2)   s[1800 + t] = bfc2[t];
    __syncthreads();

    int i = blockIdx.x * 256 + t;
    if (i >= n) return;

    float d = dis[i];
    float a[16];
    {
        const float4* ap = (const float4*)(agg_in + (size_t)i * 16);
#pragma unroll
        for (int q = 0; q < 4; q++) {
            float4 v = ap[q];
            a[4 * q + 0] = v.x; a[4 * q + 1] = v.y;
            a[4 * q + 2] = v.z; a[4 * q + 3] = v.w;
        }
    }
#pragma unroll
    for (int j = 0; j < 16; j++)
        a[j] = fmaxf(fmaf(d, a[j], s[1632 + j]), 0.f);

    float h[16];
    {
        const float4* zp = (const float4*)(Zt + (size_t)i * 16);
        float4 q0 = zp[0], q1 = zp[1], q2 = zp[2], q3 = zp[3];
        h[0] = q0.x; h[1] = q0.y; h[2]  = q0.z; h[3]  = q0.w;
        h[4] = q1.x; h[5] = q1.y; h[6]  = q1.z; h[7]  = q1.w;
        h[8] = q2.x; h[9] = q2.y; h[10] = q2.z; h[11] = q2.w;
        h[12] = q3.x; h[13] = q3.y; h[14] = q3.z; h[15] = q3.w;
    }

    float zb[16];
    if (*first) {
#pragma unroll
        for (int j = 0; j < 16; j++) zb[j] = a[j];
    } else {
        float nn[16];
#pragma unroll
        for (int j = 0; j < 16; j++) nn[j] = s[1616 + j];
#pragma unroll
        for (int kk = 0; kk < 16; kk++) {
            float hv = h[kk];
#pragma unroll
            for (int j = 0; j < 16; j++) nn[j] = fmaf(hv, s[1280 + kk * 16 + j], nn[j]);
        }
        float rr[16];
#pragma unroll
        for (int j = 0; j < 16; j++) rr[j] = s[1536 + j] + s[1552 + j];
#pragma unroll
        for (int kk = 0; kk < 16; kk++) {
            float av = a[kk], hv = h[kk];
#pragma unroll
            for (int j = 0; j < 16; j++) {
                rr[j] = fmaf(av, s[kk * 16 + j], rr[j]);
                rr[j] = fmaf(hv, s[256 + kk * 16 + j], rr[j]);
            }
        }
#pragma unroll
        for (int j = 0; j < 16; j++) rr[j] = 1.f / (1.f + __expf(-rr[j]));

        float ni[16];
#pragma unroll
        for (int j = 0; j < 16; j++) ni[j] = fmaf(rr[j], nn[j], s[1600 + j]);
#pragma unroll
        for (int kk = 0; kk < 16; kk++) {
            float av = a[kk];
#pragma unroll
            for (int j = 0; j < 16; j++) ni[j] = fmaf(av, s[1024 + kk * 16 + j], ni[j]);
        }
        float zz[16];
#pragma unroll
        for (int j = 0; j < 16; j++) zz[j] = s[1568 + j] + s[1584 + j];
#pragma unroll
        for (int kk = 0; kk < 16; kk++) {
            float av = a[kk], hv = h[kk];
#pragma unroll
            for (int j = 0; j < 16; j++) {
                zz[j] = fmaf(av, s[512 + kk * 16 + j], zz[j]);
                zz[j] = fmaf(hv, s[768 + kk * 16 + j], zz[j]);
            }
        }
#pragma unroll
        for (int j = 0; j < 16; j++) {
            float z = 1.f / (1.f + __expf(-zz[j]));
            float e = __expf(2.f * ni[j]);
            float th = 1.f - 2.f / (e + 1.f);
            zb[j] = (1.f - z) * th + z * h[j];
        }
    }

    float f1[8];
#pragma unroll
    for (int m = 0; m < 8; m++) f1[m] = s[1776 + m];
#pragma unroll
    for (int j = 0; j < 16; j++) {
        float v = zb[j];
#pragma unroll
        for (int m = 0; m < 8; m++) f1[m] = fmaf(v, s[1648 + j * 8 + m], f1[m]);
    }
#pragma unroll
    for (int m = 0; m < 8; m++) f1[m] = fmaxf(f1[m], 0.f);

    float o0 = s[1800], o1 = s[1801];
#pragma unroll
    for (int m = 0; m < 8; m++) {
        o0 = fmaf(f1[m], s[1784 + m * 2 + 0], o0);
        o1 = fmaf(f1[m], s[1784 + m * 2 + 1], o1);
    }

    ((float2*)outf)[i] = make_float2(o0, o1);
    float4* zp = (float4*)(zbar + (size_t)i * 16);
    zp[0] = make_float4(zb[0], zb[1], zb[2], zb[3]);
    zp[1] = make_float4(zb[4], zb[5], zb[6], zb[7]);
    zp[2] = make_float4(zb[8], zb[9], zb[10], zb[11]);
    zp[3] = make_float4(zb[12], zb[13], zb[14], zb[15]);
}

// ============================================================================
// FALLBACK (round-1 verified pipeline)
// ============================================================================
#define HIST_BINS 65536
#define HIST_K    32

__global__ __launch_bounds__(256) void k_hist(const int* __restrict__ col,
                                              int* __restrict__ deg, int E, int n)
{
    __shared__ uint sh[HIST_BINS / 4];
    const int t = threadIdx.x;
    const int p = blockIdx.x / HIST_K;
    const int k = blockIdx.x % HIST_K;
    const uint lo = (uint)p * HIST_BINS;
    for (int w = t; w < HIST_BINS / 4; w += 256) sh[w] = 0u;
    __syncthreads();
    const int e4 = E >> 2;
    const int4* __restrict__ c4 = (const int4*)col;
    const int STR = HIST_K * 256;
    int i = k * 256 + t;
    int4 v[8];
    for (; i + 7 * STR < e4; i += 8 * STR) {
#pragma unroll
        for (int u = 0; u < 8; u++) v[u] = c4[i + u * STR];
#pragma unroll
        for (int u = 0; u < 8; u++) {
            uint d;
            d = (uint)v[u].x - lo; if (d < HIST_BINS) atomicAdd(&sh[d >> 2], 1u << ((d & 3u) * 8u));
            d = (uint)v[u].y - lo; if (d < HIST_BINS) atomicAdd(&sh[d >> 2], 1u << ((d & 3u) * 8u));
            d = (uint)v[u].z - lo; if (d < HIST_BINS) atomicAdd(&sh[d >> 2], 1u << ((d & 3u) * 8u));
            d = (uint)v[u].w - lo; if (d < HIST_BINS) atomicAdd(&sh[d >> 2], 1u << ((d & 3u) * 8u));
        }
    }
    for (; i < e4; i += STR) {
        int4 vv = c4[i];
        uint d;
        d = (uint)vv.x - lo; if (d < HIST_BINS) atomicAdd(&sh[d >> 2], 1u << ((d & 3u) * 8u));
        d = (uint)vv.y - lo; if (d < HIST_BINS) atomicAdd(&sh[d >> 2], 1u << ((d & 3u) * 8u));
        d = (uint)vv.z - lo; if (d < HIST_BINS) atomicAdd(&sh[d >> 2], 1u << ((d & 3u) * 8u));
        d = (uint)vv.w - lo; if (d < HIST_BINS) atomicAdd(&sh[d >> 2], 1u << ((d & 3u) * 8u));
    }
    if (k == 0) {
        for (int jj = (e4 << 2) + t; jj < E; jj += 256) {
            uint d = (uint)col[jj] - lo;
            if (d < HIST_BINS) atomicAdd(&sh[d >> 2], 1u << ((d & 3u) * 8u));
        }
    }
    __syncthreads();
    for (int w = t; w < HIST_BINS / 4; w += 256) {
        uint word = sh[w];
        if (!word) continue;
        uint bb = lo + ((uint)w << 2);
#pragma unroll
        for (int b = 0; b < 4; b++) {
            uint cntv = (word >> (b * 8)) & 0xffu;
            if (cntv && bb + b < (uint)n) atomicAdd(deg + bb + b, (int)cntv);
        }
    }
}

__global__ __launch_bounds__(256) void k_pre(
    float* xm, const int* __restrict__ deg, const float* __restrict__ Wc,
    float* __restrict__ agg, int n)
{
    __shared__ float sW[256];
    int t = threadIdx.x;
    sW[t] = Wc[t];
    __syncthreads();
    int i = blockIdx.x * 256 + t;
    if (i >= n) return;
    float* xrow = xm + (size_t)i * 16;
    float xv[16];
    {
        const float4* xp = (const float4*)xrow;
        float4 q0 = xp[0], q1 = xp[1], q2 = xp[2], q3 = xp[3];
        xv[0] = q0.x; xv[1] = q0.y; xv[2]  = q0.z; xv[3]  = q0.w;
        xv[4] = q1.x; xv[5] = q1.y; xv[6]  = q1.z; xv[7]  = q1.w;
        xv[8] = q2.x; xv[9] = q2.y; xv[10] = q2.z; xv[11] = q2.w;
        xv[12] = q3.x; xv[13] = q3.y; xv[14] = q3.z; xv[15] = q3.w;
    }
    float acc[16];
#pragma unroll
    for (int jj = 0; jj < 16; jj++) acc[jj] = 0.f;
#pragma unroll
    for (int kk = 0; kk < 16; kk++) {
        float a = xv[kk];
#pragma unroll
        for (int jj = 0; jj < 16; jj++) acc[jj] = fmaf(a, sW[kk * 16 + jj], acc[jj]);
    }
    float d = rsqrtf((float)deg[i] + 1.0f);
    float v[16];
#pragma unroll
    for (int jj = 0; jj < 16; jj++) v[jj] = d * acc[jj];
    float4* ap = (float4*)(agg + (size_t)i * 16);
#pragma unroll
    for (int q = 0; q < 4; q++)
        ap[q] = make_float4(v[4 * q], v[4 * q + 1], v[4 * q + 2], v[4 * q + 3]);
    xrow[7] = d;
    uint4* yw = (uint4*)(xrow + 8);
    uint4 p0, p1;
    p0.x = pk2(v[0], v[1]);   p0.y = pk2(v[2], v[3]);
    p0.z = pk2(v[4], v[5]);   p0.w = pk2(v[6], v[7]);
    p1.x = pk2(v[8], v[9]);   p1.y = pk2(v[10], v[11]);
    p1.z = pk2(v[12], v[13]); p1.w = pk2(v[14], v[15]);
    yw[0] = p0; yw[1] = p1;
}

__global__ __launch_bounds__(256) void k_scatter(
    const int* __restrict__ row, const int* __restrict__ col,
    const float* __restrict__ xm, float* __restrict__ agg, int E, int n)
{
    uint t = blockIdx.x * 256u + threadIdx.x;
    int e = (int)(t >> 4);
    int j = (int)(t & 15u);
    if (e >= E) return;
    uint r = (uint)row[e];
    uint c = (uint)col[e];
    if (r >= (uint)n || c >= (uint)n) return;
    const ushort* yrow = (const ushort*)(xm + (size_t)r * 16 + 8);
    float v = b2f(yrow[j]);
    unsafeAtomicAdd(&agg[(size_t)c * 16 + j], v);
}

__device__ __forceinline__ void matvec16(const float* __restrict__ sW,
                                         const float* v, float* acc) {
#pragma unroll
    for (int k = 0; k < 16; k++) {
        float a = v[k];
#pragma unroll
        for (int j = 0; j < 16; j++) acc[j] = fmaf(a, sW[k * 16 + j], acc[j]);
    }
}

__global__ __launch_bounds__(256) void k_post(
    const float* __restrict__ agg_in, const float* __restrict__ xm,
    const float* __restrict__ Zt, const int* __restrict__ first,
    const float* __restrict__ bconv,
    const float* __restrict__ Wir, const float* __restrict__ bir,
    const float* __restrict__ Whr, const float* __restrict__ bhr,
    const float* __restrict__ Wiz, const float* __restrict__ biz,
    const float* __restrict__ Whz, const float* __restrict__ bhz,
    const float* __restrict__ Win, const float* __restrict__ bin_,
    const float* __restrict__ Whn, const float* __restrict__ bhn,
    const float* __restrict__ Wfc1, const float* __restrict__ bfc1,
    const float* __restrict__ Wfc2, const float* __restrict__ bfc2,
    float* outf, float* zbar, int n)
{
    __shared__ float s[1808];
    int t = threadIdx.x;
    s[t]        = Wir[t];
    s[256 + t]  = Whr[t];
    s[512 + t]  = Wiz[t];
    s[768 + t]  = Whz[t];
    s[1024 + t] = Win[t];
    s[1280 + t] = Whn[t];
    if (t < 16) {
        s[1536 + t] = bir[t];  s[1552 + t] = bhr[t];
        s[1568 + t] = biz[t];  s[1584 + t] = bhz[t];
        s[1600 + t] = bin_[t]; s[1616 + t] = bhn[t];
        s[1632 + t] = bconv[t];
        s[1784 + t] = Wfc2[t];
    }
    if (t < 128) s[1648 + t] = Wfc1[t];
    if (t < 8)   s[1776 + t] = bfc1[t];
    if (t < 2)   s[1800 + t] = bfc2[t];
    __syncthreads();
    int i = blockIdx.x * 256 + t;
    if (i >= n) return;
    float d = xm[(size_t)i * 16 + 7];
    float a[16];
    {
        const float4* ap = (const float4*)(agg_in + (size_t)i * 16);
#pragma unroll
        for (int q = 0; q < 4; q++) {
            float4 v = ap[q];
            a[4 * q + 0] = v.x; a[4 * q + 1] = v.y;
            a[4 * q + 2] = v.z; a[4 * q + 3] = v.w;
        }
    }
#pragma unroll
    for (int j = 0; j < 16; j++)
        a[j] = fmaxf(fmaf(d, a[j], s[1632 + j]), 0.f);
    float h[16];
    {
        const float4* zp = (const float4*)(Zt + (size_t)i * 16);
        float4 q0 = zp[0], q1 = zp[1], q2 = zp[2], q3 = zp[3];
        h[0] = q0.x; h[1] = q0.y; h[2]  = q0.z; h[3]  = q0.w;
        h[4] = q1.x; h[5] = q1.y; h[6]  = q1.z; h[7]  = q1.w;
        h[8] = q2.x; h[9] = q2.y; h[10] = q2.z; h[11] = q2.w;
        h[12] = q3.x; h[13] = q3.y; h[14] = q3.z; h[15] = q3.w;
    }
    float zb[16];
    if (*first) {
#pragma unroll
        for (int j = 0; j < 16; j++) zb[j] = a[j];
    } else {
        float nn[16];
#pragma unroll
        for (int j = 0; j < 16; j++) nn[j] = s[1616 + j];
        matvec16(s + 1280, h, nn);
        float rr[16];
#pragma unroll
        for (int j = 0; j < 16; j++) rr[j] = s[1536 + j] + s[1552 + j];
        matvec16(s + 0, a, rr);
        matvec16(s + 256, h, rr);
#pragma unroll
        for (int j = 0; j < 16; j++) rr[j] = 1.f / (1.f + __expf(-rr[j]));
        float ni[16];
#pragma unroll
        for (int j = 0; j < 16; j++) ni[j] = fmaf(rr[j], nn[j], s[1600 + j]);
        matvec16(s + 1024, a, ni);
        float zz[16];
#pragma unroll
        for (int j = 0; j < 16; j++) zz[j] = s[1568 + j] + s[1584 + j];
        matvec16(s + 512, a, zz);
        matvec16(s + 768, h, zz);
#pragma unroll
        for (int j = 0; j < 16; j++) {
            float z = 1.f / (1.f + __expf(-zz[j]));
            float e = __expf(2.f * ni[j]);
            float th = 1.f - 2.f / (e + 1.f);
            zb[j] = (1.f - z) * th + z * h[j];
        }
    }
    float f1[8];
#pragma unroll
    for (int m = 0; m < 8; m++) f1[m] = s[1776 + m];
#pragma unroll
    for (int j = 0; j < 16; j++) {
        float v = zb[j];
#pragma unroll
        for (int m = 0; m < 8; m++) f1[m] = fmaf(v, s[1648 + j * 8 + m], f1[m]);
    }
#pragma unroll
    for (int m = 0; m < 8; m++) f1[m] = fmaxf(f1[m], 0.f);
    float o0 = s[1800], o1 = s[1801];
#pragma unroll
    for (int m = 0; m < 8; m++) {
        o0 = fmaf(f1[m], s[1784 + m * 2 + 0], o0);
        o1 = fmaf(f1[m], s[1784 + m * 2 + 1], o1);
    }
    ((float2*)outf)[i] = make_float2(o0, o1);
    float4* zp = (float4*)(zbar + (size_t)i * 16);
    zp[0] = make_float4(zb[0], zb[1], zb[2], zb[3]);
    zp[1] = make_float4(zb[4], zb[5], zb[6], zb[7]);
    zp[2] = make_float4(zb[8], zb[9], zb[10], zb[11]);
    zp[3] = make_float4(zb[12], zb[13], zb[14], zb[15]);
}

// ============================================================================
extern "C" void kernel_launch(void* const* d_in, const int* in_sizes, int n_in,
                              void* d_out, int out_size, void* d_ws, size_t ws_size,
                              hipStream_t stream) {
    float*        x     = (float*)d_in[0];
    const int*    ei    = (const int*)d_in[1];
    const float*  Zt    = (const float*)d_in[2];
    const int*    first = (const int*)d_in[3];
    const float*  Wc    = (const float*)d_in[4];
    const float*  bconv = (const float*)d_in[5];
    const float*  Wir   = (const float*)d_in[6];
    const float*  bir   = (const float*)d_in[7];
    const float*  Whr   = (const float*)d_in[8];
    const float*  bhr   = (const float*)d_in[9];
    const float*  Wiz   = (const float*)d_in[10];
    const float*  biz   = (const float*)d_in[11];
    const float*  Whz   = (const float*)d_in[12];
    const float*  bhz   = (const float*)d_in[13];
    const float*  Win   = (const float*)d_in[14];
    const float*  bin_  = (const float*)d_in[15];
    const float*  Whn   = (const float*)d_in[16];
    const float*  bhn   = (const float*)d_in[17];
    const float*  Wfc1  = (const float*)d_in[18];
    const float*  bfc1  = (const float*)d_in[19];
    const float*  Wfc2  = (const float*)d_in[20];
    const float*  bfc2  = (const float*)d_in[21];

    int N = in_sizes[0] / 16;
    int E = in_sizes[1] / 2;

    float* outf = (float*)d_out;
    float* zbar = outf + (size_t)N * 2;
    float* agg  = zbar;

    const int* row = ei;
    const int* col = ei + E;

    int NBK = (N + 255) >> 8;          // 256-node buckets
    int NBINS = NBK;
    int SL = (E + PB - 1) / PB;

    // workspace layout (256-B aligned)
    size_t o_eb   = 0;
    size_t o_cnt  = (o_eb + (size_t)E * 4 + 255) & ~(size_t)255;
    size_t o_tot  = (o_cnt + (size_t)PB * NBINS * 2 + 255) & ~(size_t)255;
    size_t o_base = (o_tot + (size_t)NBINS * 4 + 255) & ~(size_t)255;
    size_t o_dis  = (o_base + (size_t)(NBINS + 1) * 4 + 255) & ~(size_t)255;
    size_t o_y    = (o_dis + (size_t)N * 4 + 255) & ~(size_t)255;
    size_t need   = o_y + (size_t)N * 32 + 256;

    if (N <= (1 << 20) && NBINS <= 4096 && d_ws && ws_size >= need) {
        char* ws = (char*)d_ws;
        uint*   eb    = (uint*)(ws + o_eb);
        ushort* cnt   = (ushort*)(ws + o_cnt);
        uint*   total = (uint*)(ws + o_tot);
        uint*   basep = (uint*)(ws + o_base);
        float*  dis   = (float*)(ws + o_dis);
        uint*   yws   = (uint*)(ws + o_y);

        k_bcount<<<PB, 1024, 0, stream>>>(row, col, cnt, E, N, NBINS, SL);
        k_scan1<<<(NBINS + 15) / 16, 256, 0, stream>>>(cnt, total, NBINS);
        k_scan2<<<1, 256, 0, stream>>>(total, basep, NBINS, E);
        k_part<<<PB, 1024, 0, stream>>>(row, col, cnt, basep, eb, E, N, NBINS, SL);
        k_bdeg<<<NBK, 256, 0, stream>>>(eb, basep, dis, N);
        k_pre2<<<(N + 255) / 256, 256, 0, stream>>>(x, dis, Wc, yws, N);
        k_gath<<<NBK, 256, 0, stream>>>(eb, basep, yws, agg, N);
        k_post2<<<(N + 255) / 256, 256, 0, stream>>>(agg, dis, Zt, first, bconv,
            Wir, bir, Whr, bhr, Wiz, biz, Whz, bhz, Win, bin_, Whn, bhn,
            Wfc1, bfc1, Wfc2, bfc2, outf, zbar, N);
    } else {
        // fallback: round-1 verified pipeline
        hipMemsetAsync(outf, 0, (size_t)N * 4, stream);
        int NP = (N + HIST_BINS - 1) / HIST_BINS;
        k_hist<<<NP * HIST_K, 256, 0, stream>>>(col, (int*)outf, E, N);
        k_pre<<<(N + 255) / 256, 256, 0, stream>>>(x, (const int*)outf, Wc, agg, N);
        k_scatter<<<(E + 15) / 16, 256, 0, stream>>>(row, col, x, agg, E, N);
        k_post<<<(N + 255) / 256, 256, 0, stream>>>(agg, x, Zt, first, bconv,
            Wir, bir, Whr, bhr, Wiz, biz, Whz, bhz, Win, bin_, Whn, bhn,
            Wfc1, bfc1, Wfc2, bfc2, outf, zbar, N);
    }
}

// Round 7
// 909.867 us; speedup vs baseline: 2.1583x; 2.1583x over previous
//
#include <hip/hip_runtime.h>

typedef unsigned int uint;
typedef unsigned short ushort;

// ---------- bf16 pack/unpack ----------
__device__ __forceinline__ float b2f(ushort u) {
    return __uint_as_float(((uint)u) << 16);
}
__device__ __forceinline__ uint f2bf(float f) {
    uint u = __float_as_uint(f);
    return (u + 0x7fffu + ((u >> 16) & 1u)) >> 16;
}
__device__ __forceinline__ uint pk2(float a, float b) {
    return f2bf(a) | (f2bf(b) << 16);
}

// ============================================================================
// FAST PIPELINE v5: edges counting-sorted by dst bucket of 256 nodes (global),
// then per-node inside k_gath (LDS counting sort, u32 atomics only).
// Aggregation = per-thread VGPR accumulation, ZERO f32 atomics anywhere.
// ============================================================================
#define PB 256             // partition stream slices
#define GCAP 6144          // per-chunk edge capacity in k_gath (24 KB LDS)

// ---- P1: per-(slice,bin) counts (u16 out) ----
__global__ __launch_bounds__(1024) void k_bcount(
    const int* __restrict__ row, const int* __restrict__ col,
    ushort* __restrict__ cnt, int E, int n, int NBINS, int SL)
{
    __shared__ uint h[4096];
    int t = threadIdx.x;
    for (int k = t; k < NBINS; k += 1024) h[k] = 0u;
    __syncthreads();
    int b = blockIdx.x;
    int s = b * SL;
    int end = s + SL; if (end > E) end = E;
    for (int e = s + t; e < end; e += 1024) {
        uint r = (uint)row[e], c = (uint)col[e];
        if (r < (uint)n && c < (uint)n) atomicAdd(&h[c >> 8], 1u);
    }
    __syncthreads();
    for (int k = t; k < NBINS; k += 1024)
        cnt[(size_t)b * NBINS + k] = (ushort)h[k];
}

// ---- P2a: column scan over 256 slices, 16 bins per block (LDS transpose) ----
__global__ __launch_bounds__(256) void k_scan1(
    ushort* __restrict__ cnt, uint* __restrict__ total, int NBINS)
{
    __shared__ uint tile[256 * 16];
    int t = threadIdx.x;
    int k0 = blockIdx.x * 16;
#pragma unroll
    for (int m = 0; m < 16; m++) {
        int lin = m * 256 + t;
        int b = lin >> 4, j = lin & 15;
        int k = k0 + j;
        tile[b * 16 + j] = (k < NBINS) ? (uint)cnt[(size_t)b * NBINS + k] : 0u;
    }
    __syncthreads();
    if (t < 16) {
        int k = k0 + t;
        uint run = 0u;
        for (int b = 0; b < 256; b++) {
            uint v = tile[b * 16 + t];
            tile[b * 16 + t] = run;     // exclusive prefix over slices
            run += v;
        }
        if (k < NBINS) total[k] = run;  // bin total
    }
    __syncthreads();
#pragma unroll
    for (int m = 0; m < 16; m++) {
        int lin = m * 256 + t;
        int b = lin >> 4, j = lin & 15;
        int k = k0 + j;
        if (k < NBINS) cnt[(size_t)b * NBINS + k] = (ushort)tile[b * 16 + j];
    }
}

// ---- P2b: scan bin totals -> base offsets (+sentinel base[NBINS]=E) ----
__global__ __launch_bounds__(256) void k_scan2(
    const uint* __restrict__ total, uint* __restrict__ base, int NBINS, int E)
{
    __shared__ uint ls[256];
    __shared__ uint carry;
    int t = threadIdx.x;
    if (t == 0) carry = 0u;
    __syncthreads();
    for (int off = 0; off < NBINS; off += 256) {
        int k = off + t;
        uint v = (k < NBINS) ? total[k] : 0u;
        ls[t] = v;
        __syncthreads();
        uint incl = v;
        for (int d = 1; d < 256; d <<= 1) {
            uint xv = (t >= d) ? ls[t - d] : 0u;
            __syncthreads();
            incl += xv;
            ls[t] = incl;
            __syncthreads();
        }
        if (k < NBINS) base[k] = carry + incl - v;
        __syncthreads();
        if (t == 255) carry += incl;
        __syncthreads();
    }
    if (t == 0) base[NBINS] = (uint)E;
}

// ---- P3: partition edges into bucket-sorted packed array ----
__global__ __launch_bounds__(1024) void k_part(
    const int* __restrict__ row, const int* __restrict__ col,
    const ushort* __restrict__ pos, const uint* __restrict__ base,
    uint* __restrict__ eb, int E, int n, int NBINS, int SL)
{
    __shared__ uint cur[4096];
    int t = threadIdx.x;
    int b = blockIdx.x;
    for (int k = t; k < NBINS; k += 1024)
        cur[k] = base[k] + (uint)pos[(size_t)b * NBINS + k];
    __syncthreads();
    int s = b * SL;
    int end = s + SL; if (end > E) end = E;
    for (int e = s + t; e < end; e += 1024) {
        uint r = (uint)row[e], c = (uint)col[e];
        if (r < (uint)n && c < (uint)n) {
            uint p = atomicAdd(&cur[c >> 8], 1u);
            eb[p] = (r << 8) | (c & 255u);
        }
    }
}

// ---- P4: per-bucket degree -> dis = rsqrt(deg+1) ----
__global__ __launch_bounds__(256) void k_bdeg(
    const uint* __restrict__ eb, const uint* __restrict__ base,
    float* __restrict__ dis, int n)
{
    __shared__ uint dg[256];
    int t = threadIdx.x;
    int k = blockIdx.x;
    dg[t] = 0u;
    __syncthreads();
    uint s = base[k], e_end = base[k + 1];
    for (uint i = s + t; i < e_end; i += 256)
        atomicAdd(&dg[eb[i] & 255u], 1u);
    __syncthreads();
    int i = (k << 8) + t;
    if (i < n) dis[i] = rsqrtf((float)dg[t] + 1.0f);
}

// ---- P5: xw = x@Wc, y = dis*xw (bf16 compact) ----
__global__ __launch_bounds__(256) void k_pre2(
    const float* __restrict__ xm, const float* __restrict__ dis,
    const float* __restrict__ Wc, uint* __restrict__ yws, int n)
{
    __shared__ float sW[256];
    int t = threadIdx.x;
    sW[t] = Wc[t];
    __syncthreads();
    int i = blockIdx.x * 256 + t;
    if (i >= n) return;

    const float4* xp = (const float4*)(xm + (size_t)i * 16);
    float xv[16];
    {
        float4 q0 = xp[0], q1 = xp[1], q2 = xp[2], q3 = xp[3];
        xv[0] = q0.x; xv[1] = q0.y; xv[2]  = q0.z; xv[3]  = q0.w;
        xv[4] = q1.x; xv[5] = q1.y; xv[6]  = q1.z; xv[7]  = q1.w;
        xv[8] = q2.x; xv[9] = q2.y; xv[10] = q2.z; xv[11] = q2.w;
        xv[12] = q3.x; xv[13] = q3.y; xv[14] = q3.z; xv[15] = q3.w;
    }
    float acc[16];
#pragma unroll
    for (int j = 0; j < 16; j++) acc[j] = 0.f;
#pragma unroll
    for (int k = 0; k < 16; k++) {
        float a = xv[k];
#pragma unroll
        for (int j = 0; j < 16; j++) acc[j] = fmaf(a, sW[k * 16 + j], acc[j]);
    }
    float d = dis[i];
    float v[16];
#pragma unroll
    for (int j = 0; j < 16; j++) v[j] = d * acc[j];

    uint4 p0, p1;
    p0.x = pk2(v[0], v[1]);   p0.y = pk2(v[2], v[3]);
    p0.z = pk2(v[4], v[5]);   p0.w = pk2(v[6], v[7]);
    p1.x = pk2(v[8], v[9]);   p1.y = pk2(v[10], v[11]);
    p1.z = pk2(v[12], v[13]); p1.w = pk2(v[14], v[15]);
    uint4* yw = (uint4*)(yws + (size_t)i * 8);
    yw[0] = p0; yw[1] = p1;
}

// ---- P6: per-node LDS counting sort + VGPR accumulation (no f32 atomics) ----
__device__ __forceinline__ void addy(float* acc, uint4 a, uint4 b) {
    acc[0]  += __uint_as_float(a.x << 16);
    acc[1]  += __uint_as_float(a.x & 0xffff0000u);
    acc[2]  += __uint_as_float(a.y << 16);
    acc[3]  += __uint_as_float(a.y & 0xffff0000u);
    acc[4]  += __uint_as_float(a.z << 16);
    acc[5]  += __uint_as_float(a.z & 0xffff0000u);
    acc[6]  += __uint_as_float(a.w << 16);
    acc[7]  += __uint_as_float(a.w & 0xffff0000u);
    acc[8]  += __uint_as_float(b.x << 16);
    acc[9]  += __uint_as_float(b.x & 0xffff0000u);
    acc[10] += __uint_as_float(b.y << 16);
    acc[11] += __uint_as_float(b.y & 0xffff0000u);
    acc[12] += __uint_as_float(b.z << 16);
    acc[13] += __uint_as_float(b.z & 0xffff0000u);
    acc[14] += __uint_as_float(b.w << 16);
    acc[15] += __uint_as_float(b.w & 0xffff0000u);
}

__global__ __launch_bounds__(256, 5) void k_gath(
    const uint* __restrict__ eb, const uint* __restrict__ base,
    const uint* __restrict__ yws, float* __restrict__ agg, int n)
{
    __shared__ uint srcs[GCAP];     // 24 KB: chunk edges sorted by dst node
    __shared__ uint cnt[256];
    __shared__ uint pos[256];
    __shared__ uint start[257];
    __shared__ uint ls[256];
    int t = threadIdx.x;
    int k = blockIdx.x;
    uint estart = base[k];
    uint eend   = base[k + 1];

    float acc[16];
#pragma unroll
    for (int j = 0; j < 16; j++) acc[j] = 0.f;

    for (uint cs = estart; cs < eend; cs += (uint)GCAP) {
        uint cend = cs + (uint)GCAP; if (cend > eend) cend = eend;

        // phase A: count per dst node (u32 LDS atomics)
        cnt[t] = 0u;
        __syncthreads();
        for (uint e = cs + t; e < cend; e += 256u)
            atomicAdd(&cnt[eb[e] & 255u], 1u);
        __syncthreads();

        // phase B: exclusive scan -> start[], pos[]
        uint cv = cnt[t];
        uint incl = cv;
        ls[t] = incl;
        __syncthreads();
        for (int d = 1; d < 256; d <<= 1) {
            uint xv = (t >= d) ? ls[t - d] : 0u;
            __syncthreads();
            incl += xv;
            ls[t] = incl;
            __syncthreads();
        }
        start[t] = incl - cv;
        pos[t]   = incl - cv;
        if (t == 255) start[256] = incl;
        __syncthreads();

        // phase C: scatter src ids into node-sorted order (u32 LDS atomics)
        for (uint e = cs + t; e < cend; e += 256u) {
            uint w = eb[e];
            uint p = atomicAdd(&pos[w & 255u], 1u);
            srcs[p] = w >> 8;
        }
        __syncthreads();

        // phase D: thread t accumulates its node's contiguous segment in VGPRs
        uint sBeg = start[t], sEnd = start[t + 1];
        uint e = sBeg;
        for (; e + 1 < sEnd; e += 2) {
            uint s0 = srcs[e], s1 = srcs[e + 1];
            const uint4* y0 = (const uint4*)(yws + (size_t)s0 * 8);
            const uint4* y1 = (const uint4*)(yws + (size_t)s1 * 8);
            uint4 a0 = y0[0], b0 = y0[1];
            uint4 a1 = y1[0], b1 = y1[1];
            addy(acc, a0, b0);
            addy(acc, a1, b1);
        }
        if (e < sEnd) {
            uint s0 = srcs[e];
            const uint4* y0 = (const uint4*)(yws + (size_t)s0 * 8);
            uint4 a0 = y0[0], b0 = y0[1];
            addy(acc, a0, b0);
        }
        __syncthreads();   // protect cnt/srcs for next chunk
    }

    // flush: agg[i] = acc + own y (self-loop term); pure store
    int i = (k << 8) + t;
    if (i < n) {
        const uint4* yp = (const uint4*)(yws + (size_t)i * 8);
        uint4 a = yp[0], b = yp[1];
        addy(acc, a, b);
        float4* ap = (float4*)(agg + (size_t)i * 16);
        ap[0] = make_float4(acc[0],  acc[1],  acc[2],  acc[3]);
        ap[1] = make_float4(acc[4],  acc[5],  acc[6],  acc[7]);
        ap[2] = make_float4(acc[8],  acc[9],  acc[10], acc[11]);
        ap[3] = make_float4(acc[12], acc[13], acc[14], acc[15]);
    }
}

// ---- P7: epilogue ----
__global__ __launch_bounds__(256) void k_post2(
    const float* __restrict__ agg_in, const float* __restrict__ dis,
    const float* __restrict__ Zt, const int* __restrict__ first,
    const float* __restrict__ bconv,
    const float* __restrict__ Wir, const float* __restrict__ bir,
    const float* __restrict__ Whr, const float* __restrict__ bhr,
    const float* __restrict__ Wiz, const float* __restrict__ biz,
    const float* __restrict__ Whz, const float* __restrict__ bhz,
    const float* __restrict__ Win, const float* __restrict__ bin_,
    const float* __restrict__ Whn, const float* __restrict__ bhn,
    const float* __restrict__ Wfc1, const float* __restrict__ bfc1,
    const float* __restrict__ Wfc2, const float* __restrict__ bfc2,
    float* outf, float* zbar, int n)
{
    __shared__ float s[1808];
    int t = threadIdx.x;
    s[t]        = Wir[t];
    s[256 + t]  = Whr[t];
    s[512 + t]  = Wiz[t];
    s[768 + t]  = Whz[t];
    s[1024 + t] = Win[t];
    s[1280 + t] = Whn[t];
    if (t < 16) {
        s[1536 + t] = bir[t];  s[1552 + t] = bhr[t];
        s[1568 + t] = biz[t];  s[1584 + t] = bhz[t];
        s[1600 + t] = bin_[t]; s[1616 + t] = bhn[t];
        s[1632 + t] = bconv[t];
        s[1784 + t] = Wfc2[t];
    }
    if (t < 128) s[1648 + t] = Wfc1[t];
    if (t < 8)   s[1776 + t] = bfc1[t];
    if (t < 2)   s[1800 + t] = bfc2[t];
    __syncthreads();

    int i = blockIdx.x * 256 + t;
    if (i >= n) return;

    float d = dis[i];
    float a[16];
    {
        const float4* ap = (const float4*)(agg_in + (size_t)i * 16);
#pragma unroll
        for (int q = 0; q < 4; q++) {
            float4 v = ap[q];
            a[4 * q + 0] = v.x; a[4 * q + 1] = v.y;
            a[4 * q + 2] = v.z; a[4 * q + 3] = v.w;
        }
    }
#pragma unroll
    for (int j = 0; j < 16; j++)
        a[j] = fmaxf(fmaf(d, a[j], s[1632 + j]), 0.f);

    float h[16];
    {
        const float4* zp = (const float4*)(Zt + (size_t)i * 16);
        float4 q0 = zp[0], q1 = zp[1], q2 = zp[2], q3 = zp[3];
        h[0] = q0.x; h[1] = q0.y; h[2]  = q0.z; h[3]  = q0.w;
        h[4] = q1.x; h[5] = q1.y; h[6]  = q1.z; h[7]  = q1.w;
        h[8] = q2.x; h[9] = q2.y; h[10] = q2.z; h[11] = q2.w;
        h[12] = q3.x; h[13] = q3.y; h[14] = q3.z; h[15] = q3.w;
    }

    float zb[16];
    if (*first) {
#pragma unroll
        for (int j = 0; j < 16; j++) zb[j] = a[j];
    } else {
        float nn[16];
#pragma unroll
        for (int j = 0; j < 16; j++) nn[j] = s[1616 + j];
#pragma unroll
        for (int kk = 0; kk < 16; kk++) {
            float hv = h[kk];
#pragma unroll
            for (int j = 0; j < 16; j++) nn[j] = fmaf(hv, s[1280 + kk * 16 + j], nn[j]);
        }
        float rr[16];
#pragma unroll
        for (int j = 0; j < 16; j++) rr[j] = s[1536 + j] + s[1552 + j];
#pragma unroll
        for (int kk = 0; kk < 16; kk++) {
            float av = a[kk], hv = h[kk];
#pragma unroll
            for (int j = 0; j < 16; j++) {
                rr[j] = fmaf(av, s[kk * 16 + j], rr[j]);
                rr[j] = fmaf(hv, s[256 + kk * 16 + j], rr[j]);
            }
        }
#pragma unroll
        for (int j = 0; j < 16; j++) rr[j] = 1.f / (1.f + __expf(-rr[j]));

        float ni[16];
#pragma unroll
        for (int j = 0; j < 16; j++) ni[j] = fmaf(rr[j], nn[j], s[1600 + j]);
#pragma unroll
        for (int kk = 0; kk < 16; kk++) {
            float av = a[kk];
#pragma unroll
            for (int j = 0; j < 16; j++) ni[j] = fmaf(av, s[1024 + kk * 16 + j], ni[j]);
        }
        float zz[16];
#pragma unroll
        for (int j = 0; j < 16; j++) zz[j] = s[1568 + j] + s[1584 + j];
#pragma unroll
        for (int kk = 0; kk < 16; kk++) {
            float av = a[kk], hv = h[kk];
#pragma unroll
            for (int j = 0; j < 16; j++) {
                zz[j] = fmaf(av, s[512 + kk * 16 + j], zz[j]);
                zz[j] = fmaf(hv, s[768 + kk * 16 + j], zz[j]);
            }
        }
#pragma unroll
        for (int j = 0; j < 16; j++) {
            float z = 1.f / (1.f + __expf(-zz[j]));
            float e = __expf(2.f * ni[j]);
            float th = 1.f - 2.f / (e + 1.f);
            zb[j] = (1.f - z) * th + z * h[j];
        }
    }

    float f1[8];
#pragma unroll
    for (int m = 0; m < 8; m++) f1[m] = s[1776 + m];
#pragma unroll
    for (int j = 0; j < 16; j++) {
        float v = zb[j];
#pragma unroll
        for (int m = 0; m < 8; m++) f1[m] = fmaf(v, s[1648 + j * 8 + m], f1[m]);
    }
#pragma unroll
    for (int m = 0; m < 8; m++) f1[m] = fmaxf(f1[m], 0.f);

    float o0 = s[1800], o1 = s[1801];
#pragma unroll
    for (int m = 0; m < 8; m++) {
        o0 = fmaf(f1[m], s[1784 + m * 2 + 0], o0);
        o1 = fmaf(f1[m], s[1784 + m * 2 + 1], o1);
    }

    ((float2*)outf)[i] = make_float2(o0, o1);
    float4* zp = (float4*)(zbar + (size_t)i * 16);
    zp[0] = make_float4(zb[0], zb[1], zb[2], zb[3]);
    zp[1] = make_float4(zb[4], zb[5], zb[6], zb[7]);
    zp[2] = make_float4(zb[8], zb[9], zb[10], zb[11]);
    zp[3] = make_float4(zb[12], zb[13], zb[14], zb[15]);
}

// ============================================================================
// FALLBACK (round-1 verified pipeline)
// ============================================================================
#define HIST_BINS 65536
#define HIST_K    32

__global__ __launch_bounds__(256) void k_hist(const int* __restrict__ col,
                                              int* __restrict__ deg, int E, int n)
{
    __shared__ uint sh[HIST_BINS / 4];
    const int t = threadIdx.x;
    const int p = blockIdx.x / HIST_K;
    const int k = blockIdx.x % HIST_K;
    const uint lo = (uint)p * HIST_BINS;
    for (int w = t; w < HIST_BINS / 4; w += 256) sh[w] = 0u;
    __syncthreads();
    const int e4 = E >> 2;
    const int4* __restrict__ c4 = (const int4*)col;
    const int STR = HIST_K * 256;
    int i = k * 256 + t;
    int4 v[8];
    for (; i + 7 * STR < e4; i += 8 * STR) {
#pragma unroll
        for (int u = 0; u < 8; u++) v[u] = c4[i + u * STR];
#pragma unroll
        for (int u = 0; u < 8; u++) {
            uint d;
            d = (uint)v[u].x - lo; if (d < HIST_BINS) atomicAdd(&sh[d >> 2], 1u << ((d & 3u) * 8u));
            d = (uint)v[u].y - lo; if (d < HIST_BINS) atomicAdd(&sh[d >> 2], 1u << ((d & 3u) * 8u));
            d = (uint)v[u].z - lo; if (d < HIST_BINS) atomicAdd(&sh[d >> 2], 1u << ((d & 3u) * 8u));
            d = (uint)v[u].w - lo; if (d < HIST_BINS) atomicAdd(&sh[d >> 2], 1u << ((d & 3u) * 8u));
        }
    }
    for (; i < e4; i += STR) {
        int4 vv = c4[i];
        uint d;
        d = (uint)vv.x - lo; if (d < HIST_BINS) atomicAdd(&sh[d >> 2], 1u << ((d & 3u) * 8u));
        d = (uint)vv.y - lo; if (d < HIST_BINS) atomicAdd(&sh[d >> 2], 1u << ((d & 3u) * 8u));
        d = (uint)vv.z - lo; if (d < HIST_BINS) atomicAdd(&sh[d >> 2], 1u << ((d & 3u) * 8u));
        d = (uint)vv.w - lo; if (d < HIST_BINS) atomicAdd(&sh[d >> 2], 1u << ((d & 3u) * 8u));
    }
    if (k == 0) {
        for (int jj = (e4 << 2) + t; jj < E; jj += 256) {
            uint d = (uint)col[jj] - lo;
            if (d < HIST_BINS) atomicAdd(&sh[d >> 2], 1u << ((d & 3u) * 8u));
        }
    }
    __syncthreads();
    for (int w = t; w < HIST_BINS / 4; w += 256) {
        uint word = sh[w];
        if (!word) continue;
        uint bb = lo + ((uint)w << 2);
#pragma unroll
        for (int b = 0; b < 4; b++) {
            uint cntv = (word >> (b * 8)) & 0xffu;
            if (cntv && bb + b < (uint)n) atomicAdd(deg + bb + b, (int)cntv);
        }
    }
}

__global__ __launch_bounds__(256) void k_pre(
    float* xm, const int* __restrict__ deg, const float* __restrict__ Wc,
    float* __restrict__ agg, int n)
{
    __shared__ float sW[256];
    int t = threadIdx.x;
    sW[t] = Wc[t];
    __syncthreads();
    int i = blockIdx.x * 256 + t;
    if (i >= n) return;
    float* xrow = xm + (size_t)i * 16;
    float xv[16];
    {
        const float4* xp = (const float4*)xrow;
        float4 q0 = xp[0], q1 = xp[1], q2 = xp[2], q3 = xp[3];
        xv[0] = q0.x; xv[1] = q0.y; xv[2]  = q0.z; xv[3]  = q0.w;
        xv[4] = q1.x; xv[5] = q1.y; xv[6]  = q1.z; xv[7]  = q1.w;
        xv[8] = q2.x; xv[9] = q2.y; xv[10] = q2.z; xv[11] = q2.w;
        xv[12] = q3.x; xv[13] = q3.y; xv[14] = q3.z; xv[15] = q3.w;
    }
    float acc[16];
#pragma unroll
    for (int jj = 0; jj < 16; jj++) acc[jj] = 0.f;
#pragma unroll
    for (int kk = 0; kk < 16; kk++) {
        float a = xv[kk];
#pragma unroll
        for (int jj = 0; jj < 16; jj++) acc[jj] = fmaf(a, sW[kk * 16 + jj], acc[jj]);
    }
    float d = rsqrtf((float)deg[i] + 1.0f);
    float v[16];
#pragma unroll
    for (int jj = 0; jj < 16; jj++) v[jj] = d * acc[jj];
    float4* ap = (float4*)(agg + (size_t)i * 16);
#pragma unroll
    for (int q = 0; q < 4; q++)
        ap[q] = make_float4(v[4 * q], v[4 * q + 1], v[4 * q + 2], v[4 * q + 3]);
    xrow[7] = d;
    uint4* yw = (uint4*)(xrow + 8);
    uint4 p0, p1;
    p0.x = pk2(v[0], v[1]);   p0.y = pk2(v[2], v[3]);
    p0.z = pk2(v[4], v[5]);   p0.w = pk2(v[6], v[7]);
    p1.x = pk2(v[8], v[9]);   p1.y = pk2(v[10], v[11]);
    p1.z = pk2(v[12], v[13]); p1.w = pk2(v[14], v[15]);
    yw[0] = p0; yw[1] = p1;
}

__global__ __launch_bounds__(256) void k_scatter(
    const int* __restrict__ row, const int* __restrict__ col,
    const float* __restrict__ xm, float* __restrict__ agg, int E, int n)
{
    uint t = blockIdx.x * 256u + threadIdx.x;
    int e = (int)(t >> 4);
    int j = (int)(t & 15u);
    if (e >= E) return;
    uint r = (uint)row[e];
    uint c = (uint)col[e];
    if (r >= (uint)n || c >= (uint)n) return;
    const ushort* yrow = (const ushort*)(xm + (size_t)r * 16 + 8);
    float v = b2f(yrow[j]);
    unsafeAtomicAdd(&agg[(size_t)c * 16 + j], v);
}

__device__ __forceinline__ void matvec16(const float* __restrict__ sW,
                                         const float* v, float* acc) {
#pragma unroll
    for (int k = 0; k < 16; k++) {
        float a = v[k];
#pragma unroll
        for (int j = 0; j < 16; j++) acc[j] = fmaf(a, sW[k * 16 + j], acc[j]);
    }
}

__global__ __launch_bounds__(256) void k_post(
    const float* __restrict__ agg_in, const float* __restrict__ xm,
    const float* __restrict__ Zt, const int* __restrict__ first,
    const float* __restrict__ bconv,
    const float* __restrict__ Wir, const float* __restrict__ bir,
    const float* __restrict__ Whr, const float* __restrict__ bhr,
    const float* __restrict__ Wiz, const float* __restrict__ biz,
    const float* __restrict__ Whz, const float* __restrict__ bhz,
    const float* __restrict__ Win, const float* __restrict__ bin_,
    const float* __restrict__ Whn, const float* __restrict__ bhn,
    const float* __restrict__ Wfc1, const float* __restrict__ bfc1,
    const float* __restrict__ Wfc2, const float* __restrict__ bfc2,
    float* outf, float* zbar, int n)
{
    __shared__ float s[1808];
    int t = threadIdx.x;
    s[t]        = Wir[t];
    s[256 + t]  = Whr[t];
    s[512 + t]  = Wiz[t];
    s[768 + t]  = Whz[t];
    s[1024 + t] = Win[t];
    s[1280 + t] = Whn[t];
    if (t < 16) {
        s[1536 + t] = bir[t];  s[1552 + t] = bhr[t];
        s[1568 + t] = biz[t];  s[1584 + t] = bhz[t];
        s[1600 + t] = bin_[t]; s[1616 + t] = bhn[t];
        s[1632 + t] = bconv[t];
        s[1784 + t] = Wfc2[t];
    }
    if (t < 128) s[1648 + t] = Wfc1[t];
    if (t < 8)   s[1776 + t] = bfc1[t];
    if (t < 2)   s[1800 + t] = bfc2[t];
    __syncthreads();
    int i = blockIdx.x * 256 + t;
    if (i >= n) return;
    float d = xm[(size_t)i * 16 + 7];
    float a[16];
    {
        const float4* ap = (const float4*)(agg_in + (size_t)i * 16);
#pragma unroll
        for (int q = 0; q < 4; q++) {
            float4 v = ap[q];
            a[4 * q + 0] = v.x; a[4 * q + 1] = v.y;
            a[4 * q + 2] = v.z; a[4 * q + 3] = v.w;
        }
    }
#pragma unroll
    for (int j = 0; j < 16; j++)
        a[j] = fmaxf(fmaf(d, a[j], s[1632 + j]), 0.f);
    float h[16];
    {
        const float4* zp = (const float4*)(Zt + (size_t)i * 16);
        float4 q0 = zp[0], q1 = zp[1], q2 = zp[2], q3 = zp[3];
        h[0] = q0.x; h[1] = q0.y; h[2]  = q0.z; h[3]  = q0.w;
        h[4] = q1.x; h[5] = q1.y; h[6]  = q1.z; h[7]  = q1.w;
        h[8] = q2.x; h[9] = q2.y; h[10] = q2.z; h[11] = q2.w;
        h[12] = q3.x; h[13] = q3.y; h[14] = q3.z; h[15] = q3.w;
    }
    float zb[16];
    if (*first) {
#pragma unroll
        for (int j = 0; j < 16; j++) zb[j] = a[j];
    } else {
        float nn[16];
#pragma unroll
        for (int j = 0; j < 16; j++) nn[j] = s[1616 + j];
        matvec16(s + 1280, h, nn);
        float rr[16];
#pragma unroll
        for (int j = 0; j < 16; j++) rr[j] = s[1536 + j] + s[1552 + j];
        matvec16(s + 0, a, rr);
        matvec16(s + 256, h, rr);
#pragma unroll
        for (int j = 0; j < 16; j++) rr[j] = 1.f / (1.f + __expf(-rr[j]));
        float ni[16];
#pragma unroll
        for (int j = 0; j < 16; j++) ni[j] = fmaf(rr[j], nn[j], s[1600 + j]);
        matvec16(s + 1024, a, ni);
        float zz[16];
#pragma unroll
        for (int j = 0; j < 16; j++) zz[j] = s[1568 + j] + s[1584 + j];
        matvec16(s + 512, a, zz);
        matvec16(s + 768, h, zz);
#pragma unroll
        for (int j = 0; j < 16; j++) {
            float z = 1.f / (1.f + __expf(-zz[j]));
            float e = __expf(2.f * ni[j]);
            float th = 1.f - 2.f / (e + 1.f);
            zb[j] = (1.f - z) * th + z * h[j];
        }
    }
    float f1[8];
#pragma unroll
    for (int m = 0; m < 8; m++) f1[m] = s[1776 + m];
#pragma unroll
    for (int j = 0; j < 16; j++) {
        float v = zb[j];
#pragma unroll
        for (int m = 0; m < 8; m++) f1[m] = fmaf(v, s[1648 + j * 8 + m], f1[m]);
    }
#pragma unroll
    for (int m = 0; m < 8; m++) f1[m] = fmaxf(f1[m], 0.f);
    float o0 = s[1800], o1 = s[1801];
#pragma unroll
    for (int m = 0; m < 8; m++) {
        o0 = fmaf(f1[m], s[1784 + m * 2 + 0], o0);
        o1 = fmaf(f1[m], s[1784 + m * 2 + 1], o1);
    }
    ((float2*)outf)[i] = make_float2(o0, o1);
    float4* zp = (float4*)(zbar + (size_t)i * 16);
    zp[0] = make_float4(zb[0], zb[1], zb[2], zb[3]);
    zp[1] = make_float4(zb[4], zb[5], zb[6], zb[7]);
    zp[2] = make_float4(zb[8], zb[9], zb[10], zb[11]);
    zp[3] = make_float4(zb[12], zb[13], zb[14], zb[15]);
}

// ============================================================================
extern "C" void kernel_launch(void* const* d_in, const int* in_sizes, int n_in,
                              void* d_out, int out_size, void* d_ws, size_t ws_size,
                              hipStream_t stream) {
    float*        x     = (float*)d_in[0];
    const int*    ei    = (const int*)d_in[1];
    const float*  Zt    = (const float*)d_in[2];
    const int*    first = (const int*)d_in[3];
    const float*  Wc    = (const float*)d_in[4];
    const float*  bconv = (const float*)d_in[5];
    const float*  Wir   = (const float*)d_in[6];
    const float*  bir   = (const float*)d_in[7];
    const float*  Whr   = (const float*)d_in[8];
    const float*  bhr   = (const float*)d_in[9];
    const float*  Wiz   = (const float*)d_in[10];
    const float*  biz   = (const float*)d_in[11];
    const float*  Whz   = (const float*)d_in[12];
    const float*  bhz   = (const float*)d_in[13];
    const float*  Win   = (const float*)d_in[14];
    const float*  bin_  = (const float*)d_in[15];
    const float*  Whn   = (const float*)d_in[16];
    const float*  bhn   = (const float*)d_in[17];
    const float*  Wfc1  = (const float*)d_in[18];
    const float*  bfc1  = (const float*)d_in[19];
    const float*  Wfc2  = (const float*)d_in[20];
    const float*  bfc2  = (const float*)d_in[21];

    int N = in_sizes[0] / 16;
    int E = in_sizes[1] / 2;

    float* outf = (float*)d_out;
    float* zbar = outf + (size_t)N * 2;
    float* agg  = zbar;

    const int* row = ei;
    const int* col = ei + E;

    int NBK = (N + 255) >> 8;          // 256-node buckets
    int NBINS = NBK;
    int SL = (E + PB - 1) / PB;

    // workspace layout (256-B aligned)
    size_t o_eb   = 0;
    size_t o_cnt  = (o_eb + (size_t)E * 4 + 255) & ~(size_t)255;
    size_t o_tot  = (o_cnt + (size_t)PB * NBINS * 2 + 255) & ~(size_t)255;
    size_t o_base = (o_tot + (size_t)NBINS * 4 + 255) & ~(size_t)255;
    size_t o_dis  = (o_base + (size_t)(NBINS + 1) * 4 + 255) & ~(size_t)255;
    size_t o_y    = (o_dis + (size_t)N * 4 + 255) & ~(size_t)255;
    size_t need   = o_y + (size_t)N * 32 + 256;

    if (N <= (1 << 20) && NBINS <= 4096 && d_ws && ws_size >= need) {
        char* ws = (char*)d_ws;
        uint*   eb    = (uint*)(ws + o_eb);
        ushort* cnt   = (ushort*)(ws + o_cnt);
        uint*   total = (uint*)(ws + o_tot);
        uint*   basep = (uint*)(ws + o_base);
        float*  dis   = (float*)(ws + o_dis);
        uint*   yws   = (uint*)(ws + o_y);

        k_bcount<<<PB, 1024, 0, stream>>>(row, col, cnt, E, N, NBINS, SL);
        k_scan1<<<(NBINS + 15) / 16, 256, 0, stream>>>(cnt, total, NBINS);
        k_scan2<<<1, 256, 0, stream>>>(total, basep, NBINS, E);
        k_part<<<PB, 1024, 0, stream>>>(row, col, cnt, basep, eb, E, N, NBINS, SL);
        k_bdeg<<<NBK, 256, 0, stream>>>(eb, basep, dis, N);
        k_pre2<<<(N + 255) / 256, 256, 0, stream>>>(x, dis, Wc, yws, N);
        k_gath<<<NBK, 256, 0, stream>>>(eb, basep, yws, agg, N);
        k_post2<<<(N + 255) / 256, 256, 0, stream>>>(agg, dis, Zt, first, bconv,
            Wir, bir, Whr, bhr, Wiz, biz, Whz, bhz, Win, bin_, Whn, bhn,
            Wfc1, bfc1, Wfc2, bfc2, outf, zbar, N);
    } else {
        // fallback: round-1 verified pipeline
        hipMemsetAsync(outf, 0, (size_t)N * 4, stream);
        int NP = (N + HIST_BINS - 1) / HIST_BINS;
        k_hist<<<NP * HIST_K, 256, 0, stream>>>(col, (int*)outf, E, N);
        k_pre<<<(N + 255) / 256, 256, 0, stream>>>(x, (const int*)outf, Wc, agg, N);
        k_scatter<<<(E + 15) / 16, 256, 0, stream>>>(row, col, x, agg, E, N);
        k_post<<<(N + 255) / 256, 256, 0, stream>>>(agg, x, Zt, first, bconv,
            Wir, bir, Whr, bhr, Wiz, biz, Whz, bhz, Win, bin_, Whn, bhn,
            Wfc1, bfc1, Wfc2, bfc2, outf, zbar, N);
    }
}